// Round 4
// baseline (2043.141 us; speedup 1.0000x reference)
//
#include <hip/hip_runtime.h>

#define B_ 128
#define T_ 512
#define D_ 256
#define H_ 512
#define GG_ 32   // gate groups: 16 hidden units each (32 blocks = one XCD's 32 CUs)
#define BG_ 8    // batch groups: 16 rows each (bg <-> XCD under round-robin dispatch)

typedef __bf16 bf16x8 __attribute__((ext_vector_type(8)));
typedef float  f32x4  __attribute__((ext_vector_type(4)));
typedef unsigned int u32;
typedef unsigned long long u64;
typedef u32    u32x4  __attribute__((ext_vector_type(4)));

// h exchange: T-INDEXED (no reuse => no L1/L2 staleness by construction).
// Element = (bf16 hi) | (bf16 lo << 16). 512 steps x 64K units x 4B = 128 MB.
__device__ __align__(16) u32 g_ht[(size_t)T_ * B_ * H_];
// ready flags, T-indexed PER WAVE: g_rf[t*1024 + bg*128 + gg*4 + wv].
// Producer wave sets its flag after ITS OWN h stores drained (per-wave vmcnt,
// no block barrier). Consumer wave wv polls contiguous 32 words = one 128B line.
__device__ u32 g_rf[T_ * BG_ * GG_ * 4];

__global__ void clear_flags() {
    int i = blockIdx.x * 256 + threadIdx.x;
    if (i < T_ * BG_ * GG_ * 4) g_rf[i] = 0u;
}

__device__ inline float sigmoidf_(float v) { return 1.f / (1.f + __expf(-v)); }
__device__ inline float tanhf_(float v)    { return 1.f - 2.f / (__expf(2.f * v) + 1.f); }

// Grid: 256 blocks = 8 bg x 32 gg, bg = blockIdx&7 so one bg's 32 blocks land on
// one XCD under round-robin dispatch (verified at runtime; else agent fallback).
// Block: 256 threads = 4 waves; wave w owns K-slice [w*64,+64) of D, [w*128,+128) of H
// => each wave depends on exactly 8 producer blocks x 4 producer waves (32 flags).
__global__ __launch_bounds__(256, 1)
void lstm_persistent(const float* __restrict__ x,
                     const float* __restrict__ Wih,
                     const float* __restrict__ Whh,
                     const float* __restrict__ bih,
                     const float* __restrict__ bhh,
                     float* __restrict__ out,
                     u32* __restrict__ ws)
{
    const int tid  = threadIdx.x;
    const int wv   = tid >> 6;
    const int lane = tid & 63;
    const int bg   = blockIdx.x & (BG_ - 1);   // XCD-aligned grouping
    const int gg   = blockIdx.x >> 3;

    const int lm = lane & 15;   // M/N index in 16x16 MFMA tile
    const int lq = lane >> 4;   // k-quad (k offset = lq*8)

    // ---- startup: verify all 32 blocks of this bg share one XCD ----
    __shared__ int s_mode;
    if (tid == 0) {
        const u32 xcc = __builtin_amdgcn_s_getreg((31 << 11) | 20);  // HW_REG_XCC_ID
        u32* L = ws + bg;        // leader's xcc+1
        u32* M = ws + 8 + bg;    // vote: low16 = match, high16 = mismatch
        if (gg == 0)
            __hip_atomic_store(L, xcc + 1u, __ATOMIC_RELAXED, __HIP_MEMORY_SCOPE_AGENT);
        u32 lv;
        while ((lv = __hip_atomic_load(L, __ATOMIC_RELAXED, __HIP_MEMORY_SCOPE_AGENT)) == 0u)
            __builtin_amdgcn_s_sleep(2);
        __hip_atomic_fetch_add(M, (lv == xcc + 1u) ? 1u : 0x10000u,
                               __ATOMIC_RELAXED, __HIP_MEMORY_SCOPE_AGENT);
        u32 mv;
        while ((((mv = __hip_atomic_load(M, __ATOMIC_RELAXED, __HIP_MEMORY_SCOPE_AGENT))
                 & 0xffffu) + (mv >> 16)) < (u32)GG_)
            __builtin_amdgcn_s_sleep(2);
        s_mode = (mv == (u32)GG_);
    }
    __syncthreads();
    const bool local_mode = (s_mode != 0);

    // ---- Weight B-fragments in registers (bf16 hi/lo), loaded once ----
    bf16x8 wih_hi[2][4], wih_lo[2][4];   // [kt][gt], k = wv*64 + kt*32 + lq*8
    bf16x8 whh_hi[4][4], whh_lo[4][4];   // [kt][gt], k = wv*128 + kt*32 + lq*8

    for (int gt = 0; gt < 4; ++gt) {
        const int grow = gt * 512 + gg * 16 + lm;   // gate row (type=gt, unit=gg*16+lm)
#pragma unroll
        for (int kt = 0; kt < 2; ++kt) {
            const float* p = Wih + (size_t)grow * D_ + wv * 64 + kt * 32 + lq * 8;
            bf16x8 hi, lo;
#pragma unroll
            for (int e = 0; e < 8; ++e) {
                float v = p[e];
                __bf16 h1 = (__bf16)v;
                hi[e] = h1; lo[e] = (__bf16)(v - (float)h1);
            }
            wih_hi[kt][gt] = hi; wih_lo[kt][gt] = lo;
        }
#pragma unroll
        for (int kt = 0; kt < 4; ++kt) {
            const float* p = Whh + (size_t)grow * H_ + wv * 128 + kt * 32 + lq * 8;
            bf16x8 hi, lo;
#pragma unroll
            for (int e = 0; e < 8; ++e) {
                float v = p[e];
                __bf16 h1 = (__bf16)v;
                hi[e] = h1; lo[e] = (__bf16)(v - (float)h1);
            }
            whh_hi[kt][gt] = hi; whh_lo[kt][gt] = lo;
        }
    }

    // ---- Pointwise mapping: unit pj = tid&15, batch row pb = tid>>4 ----
    const int pj = tid & 15;
    const int pb = tid >> 4;
    float bias[4];
#pragma unroll
    for (int tp = 0; tp < 4; ++tp) {
        const int r = tp * 512 + gg * 16 + pj;
        bias[tp] = bih[r] + bhh[r];
    }
    float c = 0.f;

    // double-buffered gate scratch: one __syncthreads per step (write->read);
    // WAR across steps handled by the buffer flip + next step's barrier.
    __shared__ __align__(16) float gp[2][4][64][17];   // [buf][wave][gate row][batch(+pad)]

    const int   xrow   = bg * 16 + lm;
    const float* xbase = x + (size_t)xrow * T_ * D_ + wv * 64;
    const u32 hoff_r = (u32)(bg * 16 + lm) * H_ + wv * 128;   // consumer fragment base
    const u32 hoff_w = (u32)(bg * 16 + pb) * H_ + gg * 16 + pj;

    // ---- x prefetch registers: x(t) resident in regs at top of step t.
    // Refilled AFTER the flag publish each step so the publish drain (vmcnt 0)
    // never waits on an HBM x load -- only on the single L2 h store.
    f32x4 xr0[2], xr1[2];
#pragma unroll
    for (int kt = 0; kt < 2; ++kt) {
        const float* p = xbase + kt * 32 + lq * 8;
        xr0[kt] = *(const f32x4*)p;
        xr1[kt] = *(const f32x4*)(p + 4);
    }

    for (int t = 0; t < T_; ++t) {
        f32x4 acc[4];
#pragma unroll
        for (int gt = 0; gt < 4; ++gt) acc[gt] = (f32x4){0.f, 0.f, 0.f, 0.f};

        // ---- poll FIRST: x prefetch (HBM) arrives during the spin; after the
        // flags flip, h loads issue at the earliest possible moment. ----
        u32 wd[4][8];
        if (t > 0) {
            const u32* fb = &g_rf[(u32)(t - 1) * (BG_ * GG_ * 4) + bg * (GG_ * 4) + 32 * wv];
            int spins = 0;
            while (true) {
                u32 v;
                if (spins < 256) {
                    // agent-scope load: sc0 -> L1 bypass, reads (XCD-local) L2.
                    // Coalesces: 32 lanes x 4B contiguous = one 128B request.
                    v = __hip_atomic_load(fb + (lane & 31), __ATOMIC_RELAXED,
                                          __HIP_MEMORY_SCOPE_AGENT);
                } else {
                    // progress fallback: RMW is guaranteed-fresh at L2
                    v = __hip_atomic_fetch_add((u32*)fb + (lane & 31), 0u,
                                               __ATOMIC_RELAXED, __HIP_MEMORY_SCOPE_AGENT);
                }
                if (__all(v != 0u)) break;
                __builtin_amdgcn_s_sleep(1);
                ++spins;
            }
            __builtin_amdgcn_sched_barrier(0);   // keep h loads after the poll

            const u32* hp = &g_ht[(size_t)(t - 1) * (B_ * H_) + hoff_r];
            if (local_mode) {
#pragma unroll
                for (int kt = 0; kt < 4; ++kt) {
                    u32x4 a = *(const u32x4*)(hp + kt * 32 + lq * 8);
                    u32x4 b = *(const u32x4*)(hp + kt * 32 + lq * 8 + 4);
#pragma unroll
                    for (int e = 0; e < 4; ++e) { wd[kt][e] = a[e]; wd[kt][e + 4] = b[e]; }
                }
            } else {
#pragma unroll
                for (int kt = 0; kt < 4; ++kt) {
                    const u64* q = (const u64*)(hp + kt * 32 + lq * 8);
#pragma unroll
                    for (int e = 0; e < 4; ++e) {
                        u64 v = __hip_atomic_load(q + e, __ATOMIC_RELAXED,
                                                  __HIP_MEMORY_SCOPE_AGENT);
                        wd[kt][2 * e] = (u32)v; wd[kt][2 * e + 1] = (u32)(v >> 32);
                    }
                }
            }
        }

        // ---- x-part MFMA: independent of h loads; overlaps their L2 latency ----
#pragma unroll
        for (int kt = 0; kt < 2; ++kt) {
            bf16x8 ahi, alo;
#pragma unroll
            for (int e = 0; e < 4; ++e) {
                __bf16 h1 = (__bf16)xr0[kt][e];
                ahi[e] = h1; alo[e] = (__bf16)(xr0[kt][e] - (float)h1);
                __bf16 h2 = (__bf16)xr1[kt][e];
                ahi[e + 4] = h2; alo[e + 4] = (__bf16)(xr1[kt][e] - (float)h2);
            }
#pragma unroll
            for (int gt = 0; gt < 4; ++gt) {
                acc[gt] = __builtin_amdgcn_mfma_f32_16x16x32_bf16(ahi, wih_hi[kt][gt], acc[gt], 0, 0, 0);
                acc[gt] = __builtin_amdgcn_mfma_f32_16x16x32_bf16(ahi, wih_lo[kt][gt], acc[gt], 0, 0, 0);
                acc[gt] = __builtin_amdgcn_mfma_f32_16x16x32_bf16(alo, wih_hi[kt][gt], acc[gt], 0, 0, 0);
            }
        }

        // ---- h-part MFMA ----
        if (t > 0) {
#pragma unroll
            for (int kt = 0; kt < 4; ++kt) {
                bf16x8 ahi, alo;
#pragma unroll
                for (int e = 0; e < 8; ++e) {
                    const u32 w = wd[kt][e];
                    ahi[e] = __builtin_bit_cast(__bf16, (unsigned short)(w & 0xffffu));
                    alo[e] = __builtin_bit_cast(__bf16, (unsigned short)(w >> 16));
                }
#pragma unroll
                for (int gt = 0; gt < 4; ++gt) {
                    acc[gt] = __builtin_amdgcn_mfma_f32_16x16x32_bf16(ahi, whh_hi[kt][gt], acc[gt], 0, 0, 0);
                    acc[gt] = __builtin_amdgcn_mfma_f32_16x16x32_bf16(ahi, whh_lo[kt][gt], acc[gt], 0, 0, 0);
                    acc[gt] = __builtin_amdgcn_mfma_f32_16x16x32_bf16(alo, whh_hi[kt][gt], acc[gt], 0, 0, 0);
                }
            }
        }

        // ---- cross-wave K reduction via LDS (double-buffered) ----
        const int pbuf = t & 1;
#pragma unroll
        for (int gt = 0; gt < 4; ++gt)
            *(f32x4*)&gp[pbuf][wv][gt * 16 + lm][lq * 4] = acc[gt];   // C/D: col=lm, row=lq*4+reg
        __syncthreads();

        float gate[4];
#pragma unroll
        for (int tp = 0; tp < 4; ++tp) {
            const int g = tp * 16 + pj;
            gate[tp] = gp[pbuf][0][g][pb] + gp[pbuf][1][g][pb] +
                       gp[pbuf][2][g][pb] + gp[pbuf][3][g][pb] + bias[tp];
        }
        const float ig = sigmoidf_(gate[0]);
        const float fg = sigmoidf_(gate[1]);
        const float gv = tanhf_(gate[2]);
        const float og = sigmoidf_(gate[3]);
        c = fg * c + ig * gv;
        const float h = og * tanhf_(c);

        // ---- publish h; per-wave drain (only the h store outstanding); flag ----
        const __bf16 hh = (__bf16)h;
        const __bf16 hl = (__bf16)(h - (float)hh);
        const u32 packed = (u32)__builtin_bit_cast(unsigned short, hh) |
                           ((u32)__builtin_bit_cast(unsigned short, hl) << 16);
        u32* hw = &g_ht[(size_t)t * (B_ * H_) + hoff_w];
        if (local_mode) *hw = packed;   // plain store: write-through to XCD-local L2
        else __hip_atomic_store(hw, packed, __ATOMIC_RELAXED, __HIP_MEMORY_SCOPE_AGENT);

        if (t < T_ - 1) {
            __builtin_amdgcn_sched_barrier(0);   // store must precede the drain
            __builtin_amdgcn_s_waitcnt(0);       // per-wave: h store at L2
            __builtin_amdgcn_sched_barrier(0);
            if (lane == 0) {
                u32* f = &g_rf[(u32)t * (BG_ * GG_ * 4) + bg * (GG_ * 4) + gg * 4 + wv];
                if (local_mode) *f = 1u;
                else __hip_atomic_store(f, 1u, __ATOMIC_RELAXED, __HIP_MEMORY_SCOPE_AGENT);
            }
            __builtin_amdgcn_sched_barrier(0);
        }

        // ---- x(t+1) prefetch: issued AFTER the flag; its HBM latency hides
        // under the next step's poll. out store is fire-and-forget NT. ----
        if (t < T_ - 1) {
            const float* pn = xbase + (size_t)(t + 1) * D_;
#pragma unroll
            for (int kt = 0; kt < 2; ++kt) {
                const float* p = pn + kt * 32 + lq * 8;
                xr0[kt] = *(const f32x4*)p;
                xr1[kt] = *(const f32x4*)(p + 4);
            }
        }

        __builtin_nontemporal_store(h, &out[((size_t)t * B_ + bg * 16 + pb) * H_ + gg * 16 + pj]);
    }
}

extern "C" void kernel_launch(void* const* d_in, const int* in_sizes, int n_in,
                              void* d_out, int out_size, void* d_ws, size_t ws_size,
                              hipStream_t stream) {
    const float* x   = (const float*)d_in[0];
    const float* Wih = (const float*)d_in[1];
    const float* Whh = (const float*)d_in[2];
    const float* bih = (const float*)d_in[3];
    const float* bhh = (const float*)d_in[4];
    float* out = (float*)d_out;
    u32* ws = (u32*)d_ws;

    hipMemsetAsync(d_ws, 0, 4096, stream);   // startup-vote words (ws poisoned 0xAA)
    hipLaunchKernelGGL(clear_flags, dim3((T_ * BG_ * GG_ * 4 + 255) / 256), dim3(256), 0, stream);
    hipLaunchKernelGGL(lstm_persistent, dim3(GG_ * BG_), dim3(256), 0, stream,
                       x, Wih, Whh, bih, bhh, out, ws);
}

// Round 6
// 1584.606 us; speedup vs baseline: 1.2894x; 1.2894x over previous
//
#include <hip/hip_runtime.h>

#define B_ 128
#define T_ 512
#define D_ 256
#define H_ 512
#define GG_ 32   // gate groups: 16 hidden units each (32 blocks = one XCD's 32 CUs)
#define BG_ 8    // batch groups: 16 rows each (bg <-> XCD under round-robin dispatch)

typedef __bf16 bf16x8 __attribute__((ext_vector_type(8)));
typedef float  f32x4  __attribute__((ext_vector_type(4)));
typedef unsigned int u32;
typedef unsigned long long u64;
typedef u32    u32x4  __attribute__((ext_vector_type(4)));

// h exchange: T-INDEXED (no reuse => no L1/L2 staleness by construction).
// Element = (bf16 hi) | (bf16 lo << 16). 512 steps x 64K units x 4B = 128 MB.
__device__ __align__(16) u32 g_ht[(size_t)T_ * B_ * H_];
// ready flags: PERSISTENT (not T-indexed), value = step+1, monotone.
// g_rf[bg*128 + gg*4 + wv]. The 128B flag lines are written+read every step
// => permanently L2-resident => the poll never pays an HBM cold-miss (the
// T-indexed version touched a fresh line every step: ~900cy fetch per poll).
// Consumer at step t waits for flag >= t (producer at step t-1 wrote t).
__device__ u32 g_rf[BG_ * GG_ * 4];

__global__ void clear_flags() {
    int i = blockIdx.x * 256 + threadIdx.x;
    if (i < BG_ * GG_ * 4) g_rf[i] = 0u;
}

__device__ inline float sigmoidf_(float v) { return 1.f / (1.f + __expf(-v)); }
__device__ inline float tanhf_(float v)    { return 1.f - 2.f / (__expf(2.f * v) + 1.f); }

// Grid: 256 blocks = 8 bg x 32 gg, bg = blockIdx&7 so one bg's 32 blocks land on
// one XCD under round-robin dispatch (verified at runtime; else agent fallback).
// Block: 256 threads = 4 waves; wave w owns K-slice [w*64,+64) of D, [w*128,+128) of H
// => each wave depends on exactly 8 producer blocks x 4 producer waves (32 flags).
__global__ __launch_bounds__(256, 1)
void lstm_persistent(const float* __restrict__ x,
                     const float* __restrict__ Wih,
                     const float* __restrict__ Whh,
                     const float* __restrict__ bih,
                     const float* __restrict__ bhh,
                     float* __restrict__ out,
                     u32* __restrict__ ws)
{
    const int tid  = threadIdx.x;
    const int wv   = tid >> 6;
    const int lane = tid & 63;
    const int bg   = blockIdx.x & (BG_ - 1);   // XCD-aligned grouping
    const int gg   = blockIdx.x >> 3;

    const int lm = lane & 15;   // M/N index in 16x16 MFMA tile
    const int lq = lane >> 4;   // k-quad (k offset = lq*8)

    // ---- startup: verify all 32 blocks of this bg share one XCD ----
    __shared__ int s_mode;
    if (tid == 0) {
        const u32 xcc = __builtin_amdgcn_s_getreg((31 << 11) | 20);  // HW_REG_XCC_ID
        u32* L = ws + bg;        // leader's xcc+1
        u32* M = ws + 8 + bg;    // vote: low16 = match, high16 = mismatch
        if (gg == 0)
            __hip_atomic_store(L, xcc + 1u, __ATOMIC_RELAXED, __HIP_MEMORY_SCOPE_AGENT);
        u32 lv;
        while ((lv = __hip_atomic_load(L, __ATOMIC_RELAXED, __HIP_MEMORY_SCOPE_AGENT)) == 0u)
            __builtin_amdgcn_s_sleep(2);
        __hip_atomic_fetch_add(M, (lv == xcc + 1u) ? 1u : 0x10000u,
                               __ATOMIC_RELAXED, __HIP_MEMORY_SCOPE_AGENT);
        u32 mv;
        while ((((mv = __hip_atomic_load(M, __ATOMIC_RELAXED, __HIP_MEMORY_SCOPE_AGENT))
                 & 0xffffu) + (mv >> 16)) < (u32)GG_)
            __builtin_amdgcn_s_sleep(2);
        s_mode = (mv == (u32)GG_);
    }
    __syncthreads();
    const bool local_mode = (s_mode != 0);

    // ---- Weight B-fragments in registers (bf16 hi/lo), loaded once ----
    bf16x8 wih_hi[2][4], wih_lo[2][4];   // [kt][gt], k = wv*64 + kt*32 + lq*8
    bf16x8 whh_hi[4][4], whh_lo[4][4];   // [kt][gt], k = wv*128 + kt*32 + lq*8

    for (int gt = 0; gt < 4; ++gt) {
        const int grow = gt * 512 + gg * 16 + lm;   // gate row (type=gt, unit=gg*16+lm)
#pragma unroll
        for (int kt = 0; kt < 2; ++kt) {
            const float* p = Wih + (size_t)grow * D_ + wv * 64 + kt * 32 + lq * 8;
            bf16x8 hi, lo;
#pragma unroll
            for (int e = 0; e < 8; ++e) {
                float v = p[e];
                __bf16 h1 = (__bf16)v;
                hi[e] = h1; lo[e] = (__bf16)(v - (float)h1);
            }
            wih_hi[kt][gt] = hi; wih_lo[kt][gt] = lo;
        }
#pragma unroll
        for (int kt = 0; kt < 4; ++kt) {
            const float* p = Whh + (size_t)grow * H_ + wv * 128 + kt * 32 + lq * 8;
            bf16x8 hi, lo;
#pragma unroll
            for (int e = 0; e < 8; ++e) {
                float v = p[e];
                __bf16 h1 = (__bf16)v;
                hi[e] = h1; lo[e] = (__bf16)(v - (float)h1);
            }
            whh_hi[kt][gt] = hi; whh_lo[kt][gt] = lo;
        }
    }

    // ---- Pointwise mapping: unit pj = tid&15, batch row pb = tid>>4 ----
    const int pj = tid & 15;
    const int pb = tid >> 4;
    float bias[4];
#pragma unroll
    for (int tp = 0; tp < 4; ++tp) {
        const int r = tp * 512 + gg * 16 + pj;
        bias[tp] = bih[r] + bhh[r];
    }
    float c = 0.f;

    // double-buffered gate scratch: one __syncthreads per step (write->read);
    // WAR across steps handled by the buffer flip + next step's barrier.
    __shared__ __align__(16) float gp[2][4][64][17];   // [buf][wave][gate row][batch(+pad)]

    const int   xrow   = bg * 16 + lm;
    const float* xbase = x + (size_t)xrow * T_ * D_ + wv * 64;
    const u32 hoff_r = (u32)(bg * 16 + lm) * H_ + wv * 128;   // consumer fragment base
    const u32 hoff_w = (u32)(bg * 16 + pb) * H_ + gg * 16 + pj;

    // ---- x prefetch registers (x(t) resident in regs at top of step t) ----
    f32x4 xr0[2], xr1[2], xn0[2], xn1[2];
#pragma unroll
    for (int kt = 0; kt < 2; ++kt) {
        const float* p = xbase + kt * 32 + lq * 8;
        xr0[kt] = *(const f32x4*)p;
        xr1[kt] = *(const f32x4*)(p + 4);
    }

    for (int t = 0; t < T_; ++t) {
        f32x4 acc[4];
#pragma unroll
        for (int gt = 0; gt < 4; ++gt) acc[gt] = (f32x4){0.f, 0.f, 0.f, 0.f};

        // ---- x-part from prefetched registers ----
#pragma unroll
        for (int kt = 0; kt < 2; ++kt) {
            bf16x8 ahi, alo;
#pragma unroll
            for (int e = 0; e < 4; ++e) {
                __bf16 h1 = (__bf16)xr0[kt][e];
                ahi[e] = h1; alo[e] = (__bf16)(xr0[kt][e] - (float)h1);
                __bf16 h2 = (__bf16)xr1[kt][e];
                ahi[e + 4] = h2; alo[e + 4] = (__bf16)(xr1[kt][e] - (float)h2);
            }
#pragma unroll
            for (int gt = 0; gt < 4; ++gt) {
                acc[gt] = __builtin_amdgcn_mfma_f32_16x16x32_bf16(ahi, wih_hi[kt][gt], acc[gt], 0, 0, 0);
                acc[gt] = __builtin_amdgcn_mfma_f32_16x16x32_bf16(ahi, wih_lo[kt][gt], acc[gt], 0, 0, 0);
                acc[gt] = __builtin_amdgcn_mfma_f32_16x16x32_bf16(alo, wih_hi[kt][gt], acc[gt], 0, 0, 0);
            }
        }

        // ---- h-part: coalesced load-poll of 32 per-wave producer flags.
        // Flags hold step+1 (monotone); line is L2-hot (no per-step cold miss).
        if (t > 0) {
            const u32 tval = (u32)t;
            const u32* fb = &g_rf[bg * (GG_ * 4) + 32 * wv];
            int spins = 0;
            while (true) {
                u32 v;
                if (spins < 256) {
                    // agent-scope load: sc0 -> L1 bypass, reads (XCD-local) L2.
                    // Coalesces: 32 lanes x 4B contiguous = one 128B request.
                    v = __hip_atomic_load(fb + (lane & 31), __ATOMIC_RELAXED,
                                          __HIP_MEMORY_SCOPE_AGENT);
                } else {
                    // progress fallback: RMW is guaranteed-fresh at L2
                    v = __hip_atomic_fetch_add((u32*)fb + (lane & 31), 0u,
                                               __ATOMIC_RELAXED, __HIP_MEMORY_SCOPE_AGENT);
                }
                if (__all(v >= tval)) break;
                __builtin_amdgcn_s_sleep(1);
                ++spins;
            }
            __builtin_amdgcn_sched_barrier(0);   // keep h loads after the poll

            const u32* hp = &g_ht[(size_t)(t - 1) * (B_ * H_) + hoff_r];
            u32 wd[4][8];
            if (local_mode) {
#pragma unroll
                for (int kt = 0; kt < 4; ++kt) {
                    u32x4 a = *(const u32x4*)(hp + kt * 32 + lq * 8);
                    u32x4 b = *(const u32x4*)(hp + kt * 32 + lq * 8 + 4);
#pragma unroll
                    for (int e = 0; e < 4; ++e) { wd[kt][e] = a[e]; wd[kt][e + 4] = b[e]; }
                }
            } else {
#pragma unroll
                for (int kt = 0; kt < 4; ++kt) {
                    const u64* q = (const u64*)(hp + kt * 32 + lq * 8);
#pragma unroll
                    for (int e = 0; e < 4; ++e) {
                        u64 v = __hip_atomic_load(q + e, __ATOMIC_RELAXED,
                                                  __HIP_MEMORY_SCOPE_AGENT);
                        wd[kt][2 * e] = (u32)v; wd[kt][2 * e + 1] = (u32)(v >> 32);
                    }
                }
            }

#pragma unroll
            for (int kt = 0; kt < 4; ++kt) {
                bf16x8 ahi, alo;
#pragma unroll
                for (int e = 0; e < 8; ++e) {
                    const u32 w = wd[kt][e];
                    ahi[e] = __builtin_bit_cast(__bf16, (unsigned short)(w & 0xffffu));
                    alo[e] = __builtin_bit_cast(__bf16, (unsigned short)(w >> 16));
                }
#pragma unroll
                for (int gt = 0; gt < 4; ++gt) {
                    acc[gt] = __builtin_amdgcn_mfma_f32_16x16x32_bf16(ahi, whh_hi[kt][gt], acc[gt], 0, 0, 0);
                    acc[gt] = __builtin_amdgcn_mfma_f32_16x16x32_bf16(ahi, whh_lo[kt][gt], acc[gt], 0, 0, 0);
                    acc[gt] = __builtin_amdgcn_mfma_f32_16x16x32_bf16(alo, whh_hi[kt][gt], acc[gt], 0, 0, 0);
                }
            }
        }

        // ---- x(t+1) prefetch: latency hides under LDS reduce + pointwise ----
        __builtin_amdgcn_sched_barrier(0);   // don't let these hoist into the h-load wait
        if (t < T_ - 1) {
            const float* pn = xbase + (size_t)(t + 1) * D_;
#pragma unroll
            for (int kt = 0; kt < 2; ++kt) {
                const float* p = pn + kt * 32 + lq * 8;
                xn0[kt] = *(const f32x4*)p;
                xn1[kt] = *(const f32x4*)(p + 4);
            }
        }
        __builtin_amdgcn_sched_barrier(0);

        // ---- cross-wave K reduction via LDS (double-buffered) ----
        const int pbuf = t & 1;
#pragma unroll
        for (int gt = 0; gt < 4; ++gt)
            *(f32x4*)&gp[pbuf][wv][gt * 16 + lm][lq * 4] = acc[gt];   // C/D: col=lm, row=lq*4+reg
        __syncthreads();

        float gate[4];
#pragma unroll
        for (int tp = 0; tp < 4; ++tp) {
            const int g = tp * 16 + pj;
            gate[tp] = gp[pbuf][0][g][pb] + gp[pbuf][1][g][pb] +
                       gp[pbuf][2][g][pb] + gp[pbuf][3][g][pb] + bias[tp];
        }
        const float ig = sigmoidf_(gate[0]);
        const float fg = sigmoidf_(gate[1]);
        const float gv = tanhf_(gate[2]);
        const float og = sigmoidf_(gate[3]);
        c = fg * c + ig * gv;
        const float h = og * tanhf_(c);

        // ---- publish h; per-wave drain; per-wave flag = t+1; out store last ----
        const __bf16 hh = (__bf16)h;
        const __bf16 hl = (__bf16)(h - (float)hh);
        const u32 packed = (u32)__builtin_bit_cast(unsigned short, hh) |
                           ((u32)__builtin_bit_cast(unsigned short, hl) << 16);
        u32* hw = &g_ht[(size_t)t * (B_ * H_) + hoff_w];
        if (local_mode) *hw = packed;   // plain store: write-through to XCD-local L2
        else __hip_atomic_store(hw, packed, __ATOMIC_RELAXED, __HIP_MEMORY_SCOPE_AGENT);

        if (t < T_ - 1) {
            __builtin_amdgcn_sched_barrier(0);   // store must precede the drain
            __builtin_amdgcn_s_waitcnt(0);       // per-wave: h store (+prefetch) at L2
            __builtin_amdgcn_sched_barrier(0);
            if (lane == 0) {
                u32* f = &g_rf[bg * (GG_ * 4) + gg * 4 + wv];
                if (local_mode) *f = (u32)(t + 1);
                else __hip_atomic_store(f, (u32)(t + 1), __ATOMIC_RELAXED, __HIP_MEMORY_SCOPE_AGENT);
            }
            __builtin_amdgcn_sched_barrier(0);
        }

        __builtin_nontemporal_store(h, &out[((size_t)t * B_ + bg * 16 + pb) * H_ + gg * 16 + pj]);

        // rotate x prefetch registers
#pragma unroll
        for (int kt = 0; kt < 2; ++kt) { xr0[kt] = xn0[kt]; xr1[kt] = xn1[kt]; }
    }
}

extern "C" void kernel_launch(void* const* d_in, const int* in_sizes, int n_in,
                              void* d_out, int out_size, void* d_ws, size_t ws_size,
                              hipStream_t stream) {
    const float* x   = (const float*)d_in[0];
    const float* Wih = (const float*)d_in[1];
    const float* Whh = (const float*)d_in[2];
    const float* bih = (const float*)d_in[3];
    const float* bhh = (const float*)d_in[4];
    float* out = (float*)d_out;
    u32* ws = (u32*)d_ws;

    hipMemsetAsync(d_ws, 0, 4096, stream);   // startup-vote words (ws poisoned 0xAA)
    hipLaunchKernelGGL(clear_flags, dim3((BG_ * GG_ * 4 + 255) / 256), dim3(256), 0, stream);
    hipLaunchKernelGGL(lstm_persistent, dim3(GG_ * BG_), dim3(256), 0, stream,
                       x, Wih, Whh, bih, bhh, out, ws);
}